// Round 2
// baseline (273.656 us; speedup 1.0000x reference)
//
#include <hip/hip_runtime.h>

// OccupancyToTopology: for each of 64^3 cells, emit the 256-entry
// tensor-product table over its 8 corner occupancy probabilities.
//
// Layout: one 64-lane wave per cell. lane i handles t = 4i .. 4i+3:
//   bit c of t (c>=2) == bit (c-2) of lane  -> 6-factor "base" product
//   bits 0,1 of t enumerate the four p0/p1 combinations -> float4 store
// Each wave writes the cell's contiguous 1 KiB output row fully coalesced.

__global__ __launch_bounds__(256) void
occ_topo_kernel(const float* __restrict__ occ, float* __restrict__ out, int n_cells)
{
    const int lane   = threadIdx.x & 63;
    const int waveInBlk = threadIdx.x >> 6;
    const int wavesPerBlk = blockDim.x >> 6;          // 4
    const int totalWaves  = gridDim.x * wavesPerBlk;
    int wave_id = blockIdx.x * wavesPerBlk + waveInBlk;

    const int S1 = 65, S2 = 65 * 65;

    for (int cell = wave_id; cell < n_cells; cell += totalWaves) {
        // cell -> (x,y,z) in the 64^3 interior grid (reshape(-1) order)
        int z = cell & 63;
        int y = (cell >> 6) & 63;
        int x = cell >> 12;
        int base = x * S2 + y * S1 + z;

        // CORNER_OFFSETS order:
        // c0 (0,0,0)  c1 (1,0,0)  c2 (1,1,0)  c3 (0,1,0)
        // c4 (0,0,1)  c5 (1,0,1)  c6 (1,1,1)  c7 (0,1,1)
        float p0 = occ[base];
        float p1 = occ[base + S2];
        float p2 = occ[base + S2 + S1];
        float p3 = occ[base + S1];
        float p4 = occ[base + 1];
        float p5 = occ[base + S2 + 1];
        float p6 = occ[base + S2 + S1 + 1];
        float p7 = occ[base + S1 + 1];

        // base product from lane bits (bits 2..7 of t)
        float f2 = (lane & 1)  ? p2 : 1.0f - p2;
        float f3 = (lane & 2)  ? p3 : 1.0f - p3;
        float f4 = (lane & 4)  ? p4 : 1.0f - p4;
        float f5 = (lane & 8)  ? p5 : 1.0f - p5;
        float f6 = (lane & 16) ? p6 : 1.0f - p6;
        float f7 = (lane & 32) ? p7 : 1.0f - p7;
        float bp = ((f2 * f3) * (f4 * f5)) * (f6 * f7);

        float q0 = 1.0f - p0;
        float q1 = 1.0f - p1;
        float4 v;
        v.x = bp * (q0 * q1);   // t bits (0,0)
        v.y = bp * (p0 * q1);   // t bits (1,0)
        v.z = bp * (q0 * p1);   // t bits (0,1)
        v.w = bp * (p0 * p1);   // t bits (1,1)

        float4* outp = reinterpret_cast<float4*>(out + (size_t)cell * 256) + lane;
        *outp = v;
    }
}

extern "C" void kernel_launch(void* const* d_in, const int* in_sizes, int n_in,
                              void* d_out, int out_size, void* d_ws, size_t ws_size,
                              hipStream_t stream)
{
    const float* occ = (const float*)d_in[0];
    float* out = (float*)d_out;
    const int n_cells = 64 * 64 * 64;          // (65-1)^3

    const int block = 256;                     // 4 waves/block
    const int grid  = 2048;                    // 256 CU * 8 blocks, grid-stride
    occ_topo_kernel<<<grid, block, 0, stream>>>(occ, out, n_cells);
}